// Round 5
// baseline (324.991 us; speedup 1.0000x reference)
//
#include <hip/hip_runtime.h>
#include <hip/hip_cooperative_groups.h>
#include <math.h>

namespace cg = cooperative_groups;

#define BB 4
#define TT 128
#define DD 768
#define HD 770
#define HP 800
#define LL 40
#define TP1 129

typedef __attribute__((ext_vector_type(8))) short s16x8;
typedef __attribute__((ext_vector_type(4))) float f32x4;

// ws float offsets
#define P_OFF   0
#define Q_OFF   409600          // 512*800
#define W2F_OFF 819200          // 4800 uint4  = 19200 u32
#define BF1_OFF 838400          // 150528 uint4 = 602112 u32
#define AF_OFF  1440512         // 49152 uint4  = 196608 u32
#define ACC_OFF 1637120         // 160 floats
// total ~1637280 floats = 6.55 MB

__device__ __forceinline__ unsigned pkbf(float a, float b) {
    unsigned ua = __float_as_uint(a);
    unsigned ub = __float_as_uint(b);
    return ((ua + 0x8000u) >> 16) | ((ub + 0x8000u) & 0xffff0000u);
}
__device__ __forceinline__ unsigned rne1(float v) {
    unsigned x = __float_as_uint(v);
    return (x + 0x7fffu + ((x >> 16) & 1u)) >> 16;
}

__global__ __launch_bounds__(256, 2) void kFused(
    const float* __restrict__ hidden, const float* __restrict__ W1,
    const float* __restrict__ W2, const float* __restrict__ b1,
    const float* __restrict__ b2, const int* __restrict__ spans,
    const int* __restrict__ avail, float* __restrict__ out,
    float* __restrict__ ws)
{
    __shared__ unsigned Sb[2][128 * 20];
    __shared__ float var[3 * HP];
    __shared__ int avi[TT];
    __shared__ float sred[192];

    cg::grid_group grid = cg::this_grid();

    float*    P     = ws + P_OFF;
    float*    Q     = ws + Q_OFF;
    unsigned* W2f   = (unsigned*)(ws + W2F_OFF);
    unsigned* Bf1   = (unsigned*)(ws + BF1_OFF);
    unsigned* Af    = (unsigned*)(ws + AF_OFF);
    float*    accum = ws + ACC_OFF;

    const int tid  = threadIdx.x;
    const int g    = blockIdx.x * 256 + tid;    // 0..131071
    const int wave = tid >> 6;
    const int lane = tid & 63;

    // ===================== Phase 0: prep =====================
    // W1 -> Bf1 fragments (150528 uint4 tasks)
    for (int u = g; u < 150528; u += 131072) {
        int ln = u & 63;
        int gi = u >> 6;              // 0..2351
        int ks = gi % 24;
        int g2 = gi / 24;
        int nt = g2 % 49;
        int half = g2 / 49;
        int kbase = ks * 32 + ((ln >> 4) << 3);
        int h = nt * 16 + (ln & 15);
        int row0 = half * DD + kbase;
        unsigned pk[4];
        #pragma unroll
        for (int sp = 0; sp < 4; ++sp) {
            unsigned w[2];
            #pragma unroll
            for (int e = 0; e < 2; ++e) {
                float v = (h < HD) ? W1[(size_t)(row0 + 2 * sp + e) * HD + h] : 0.0f;
                w[e] = rne1(v);
            }
            pk[sp] = w[0] | (w[1] << 16);
        }
        ((uint4*)Bf1)[u] = make_uint4(pk[0], pk[1], pk[2], pk[3]);
    }
    // hidden -> Af fragments (49152 uint4 tasks)
    if (g < 49152) {
        int ln = g & 63;
        int fi = g >> 6;              // 0..767
        int ks = fi % 24;
        int mband = fi / 24;          // 0..31
        int b = mband >> 3;
        int tt = mband & 7;
        int m = ln & 15;
        int kb = ks * 32 + ((ln >> 4) << 3);
        const float* src = hidden + (size_t)(b * TP1 + 1 + tt * 16 + m) * DD + kb;
        float4 x0 = ((const float4*)src)[0];
        float4 x1 = ((const float4*)src)[1];
        ((uint4*)Af)[g] = make_uint4(pkbf(x0.x, x0.y), pkbf(x0.z, x0.w),
                                     pkbf(x1.x, x1.y), pkbf(x1.z, x1.w));
    }
    // W2 -> W2f fragments (4800 uint4 tasks)
    if (g < 4800) {
        int nt = g / 1600;
        int rem = g - nt * 1600;
        int ks = rem >> 6;
        int ln = rem & 63;
        int kbase = ks * 32 + ((ln >> 4) << 3);
        int l = nt * 16 + (ln & 15);
        unsigned pk[4];
        #pragma unroll
        for (int sp = 0; sp < 4; ++sp) {
            unsigned w[2];
            #pragma unroll
            for (int e = 0; e < 2; ++e) {
                int k = kbase + 2 * sp + e;
                float v = (k < HD && l < LL) ? W2[k * LL + l] : 0.0f;
                w[e] = rne1(v);
            }
            pk[sp] = w[0] | (w[1] << 16);
        }
        ((uint4*)W2f)[g] = make_uint4(pk[0], pk[1], pk[2], pk[3]);
    }
    // Q pad columns [768,800) zero (phase 1 overwrites [768,770))
    if (g < 16384) {
        int row = g >> 5;
        Q[(size_t)row * HP + 768 + (g & 31)] = 0.0f;
    }
    // accum zero
    if (g < 160) accum[g] = 0.0f;

    grid.sync();

    // ===================== Phase 1: X@W1 GEMM (P,Q) =====================
    {
        const int gw = blockIdx.x * 4 + wave;   // 0..2047
        if (gw < 1568) {
            const int mband = gw & 31;
            const int nt = gw >> 5;             // 0..48
            const int b = mband >> 3;
            const int tt = mband & 7;

            const uint4* __restrict__ A0 = (const uint4*)Af + (size_t)mband * 24 * 64 + lane;
            const uint4* __restrict__ B0 = (const uint4*)Bf1 + ((size_t)nt * 24) * 64 + lane;
            const uint4* __restrict__ B1 = (const uint4*)Bf1 + ((size_t)(49 + nt) * 24) * 64 + lane;

            f32x4 a0 = (f32x4){0.f, 0.f, 0.f, 0.f};
            f32x4 a1 = (f32x4){0.f, 0.f, 0.f, 0.f};

            #pragma unroll 4
            for (int ks = 0; ks < 24; ++ks) {
                union { uint4 q; s16x8 v; } af, bf0, bf1;
                af.q  = A0[ks * 64];
                bf0.q = B0[ks * 64];
                bf1.q = B1[ks * 64];
                a0 = __builtin_amdgcn_mfma_f32_16x16x32_bf16(af.v, bf0.v, a0, 0, 0, 0);
                a1 = __builtin_amdgcn_mfma_f32_16x16x32_bf16(af.v, bf1.v, a1, 0, 0, 0);
            }

            const int col = lane & 15;
            const int h = nt * 16 + col;
            if (h < HD) {
                const float bv = b1[h];
                const int quad = lane >> 4;
                #pragma unroll
                for (int r = 0; r < 4; ++r) {
                    int t = tt * 16 + quad * 4 + r;
                    size_t row = (size_t)(b * TT + t) * HP;
                    P[row + h] = a0[r] + bv;
                    Q[row + h] = a1[r];
                }
            }
        }
    }

    grid.sync();

    // ===================== Phase 2: big GEMM + exp-sum =====================
    {
        const int i = blockIdx.x & 127;
        const int b = blockIdx.x >> 7;

        const int start = spans[b * 2];
        const int end   = spans[b * 2 + 1];

        const int jS = tid >> 1;
        const int hh = (tid & 1) << 4;
        int indS;
        {
            bool isfull = (i == start) && (jS == end);
            bool inside = (start <= i) && (i <= jS) && (jS <= end) && !isfull;
            indS = isfull ? 2 : (inside ? 1 : 0);
        }

        {
            const float* Pi  = P + (size_t)(b * TT + i) * HP;
            const float* w1L = W1 + (size_t)2 * DD * HD;
            for (int h = tid; h < HP; h += 256) {
                float pv = (h < HD) ? Pi[h] : 0.0f;
                float wv = (h < HD) ? w1L[h] : 0.0f;
                var[h]        = pv;
                var[HP + h]   = pv + wv;
                var[2*HP + h] = pv + wv + wv;
            }
            if (tid < TT) avi[tid] = avail[i * TT + tid];
        }
        __syncthreads();

        const float* Qj = Q + (size_t)(b * TT + jS) * HP;
        const float* vb = var + indS * HP;

        auto form = [&](int c, int p) {
            const int h0 = c * 32 + hh;
            const float4* qp = (const float4*)(Qj + h0);
            float4 q0 = qp[0], q1 = qp[1], q2 = qp[2], q3 = qp[3];
            const float4* vp = (const float4*)(vb + h0);
            float4 v0 = vp[0], v1 = vp[1], v2 = vp[2], v3 = vp[3];
            float s0 = fmaxf(v0.x + q0.x, 0.f), s1 = fmaxf(v0.y + q0.y, 0.f);
            float s2 = fmaxf(v0.z + q0.z, 0.f), s3 = fmaxf(v0.w + q0.w, 0.f);
            float s4 = fmaxf(v1.x + q1.x, 0.f), s5 = fmaxf(v1.y + q1.y, 0.f);
            float s6 = fmaxf(v1.z + q1.z, 0.f), s7 = fmaxf(v1.w + q1.w, 0.f);
            float s8 = fmaxf(v2.x + q2.x, 0.f), s9 = fmaxf(v2.y + q2.y, 0.f);
            float sa = fmaxf(v2.z + q2.z, 0.f), sb_ = fmaxf(v2.w + q2.w, 0.f);
            float sc = fmaxf(v3.x + q3.x, 0.f), sd = fmaxf(v3.y + q3.y, 0.f);
            float se = fmaxf(v3.z + q3.z, 0.f), sf = fmaxf(v3.w + q3.w, 0.f);
            uint4* dst = (uint4*)(&Sb[p][jS * 20 + (hh >> 1)]);
            dst[0] = make_uint4(pkbf(s0,s1), pkbf(s2,s3), pkbf(s4,s5), pkbf(s6,s7));
            dst[1] = make_uint4(pkbf(s8,s9), pkbf(sa,sb_), pkbf(sc,sd), pkbf(se,sf));
        };

        f32x4 acc[2][3];
        #pragma unroll
        for (int mt = 0; mt < 2; ++mt)
            #pragma unroll
            for (int nt = 0; nt < 3; ++nt)
                acc[mt][nt] = (f32x4){0.f, 0.f, 0.f, 0.f};

        form(0, 0);
        __syncthreads();

        const int arow0 = (wave * 32 + (lane & 15)) * 20 + ((lane >> 4) << 2);
        for (int c = 0; c < 25; ++c) {
            const int p = c & 1;
            s16x8 bf0 = *(const s16x8*)((const unsigned*)W2f + (( 0 + c) * 64 + lane) * 4);
            s16x8 bf1 = *(const s16x8*)((const unsigned*)W2f + ((25 + c) * 64 + lane) * 4);
            s16x8 bf2 = *(const s16x8*)((const unsigned*)W2f + ((50 + c) * 64 + lane) * 4);
            s16x8 af0 = *(const s16x8*)(&Sb[p][arow0]);
            s16x8 af1 = *(const s16x8*)(&Sb[p][arow0 + 16 * 20]);
            if (c + 1 < 25) form(c + 1, p ^ 1);
            acc[0][0] = __builtin_amdgcn_mfma_f32_16x16x32_bf16(af0, bf0, acc[0][0], 0, 0, 0);
            acc[0][1] = __builtin_amdgcn_mfma_f32_16x16x32_bf16(af0, bf1, acc[0][1], 0, 0, 0);
            acc[0][2] = __builtin_amdgcn_mfma_f32_16x16x32_bf16(af0, bf2, acc[0][2], 0, 0, 0);
            acc[1][0] = __builtin_amdgcn_mfma_f32_16x16x32_bf16(af1, bf0, acc[1][0], 0, 0, 0);
            acc[1][1] = __builtin_amdgcn_mfma_f32_16x16x32_bf16(af1, bf1, acc[1][1], 0, 0, 0);
            acc[1][2] = __builtin_amdgcn_mfma_f32_16x16x32_bf16(af1, bf2, acc[1][2], 0, 0, 0);
            __syncthreads();
        }

        float bias[3];
        #pragma unroll
        for (int nt = 0; nt < 3; ++nt) {
            int l = nt * 16 + (lane & 15);
            bias[nt] = (l < LL) ? b2[l] : 0.0f;
        }
        const int jr0 = wave * 32 + ((lane >> 4) << 2);
        float sE[3] = {0.f, 0.f, 0.f};
        #pragma unroll
        for (int mt = 0; mt < 2; ++mt) {
            #pragma unroll
            for (int r = 0; r < 4; ++r) {
                int j = jr0 + mt * 16 + r;
                bool msk = avi[j] >= 1;
                size_t rowoff = ((size_t)(b * (TT * TT) + i * TT + j)) * LL;
                #pragma unroll
                for (int nt = 0; nt < 3; ++nt) {
                    int l = nt * 16 + (lane & 15);
                    if (l < LL) {
                        float val = msk ? (acc[mt][nt][r] + bias[nt]) : 0.0f;
                        out[rowoff + l] = val;
                        sE[nt] += __expf(val);
                    }
                }
            }
        }
        #pragma unroll
        for (int nt = 0; nt < 3; ++nt) {
            float v = sE[nt];
            v += __shfl_xor(v, 16);
            v += __shfl_xor(v, 32);
            if (lane < 16) sred[wave * 48 + nt * 16 + lane] = v;
        }
        __syncthreads();
        if (tid < 48) {
            float t4 = sred[tid] + sred[48 + tid] + sred[96 + tid] + sred[144 + tid];
            if (tid < LL) atomicAdd(&accum[b * LL + tid], t4);
        }
    }

    grid.sync();

    // ===================== Phase 3: out -= log(denom) =====================
    #pragma unroll
    for (int it = 0; it < 5; ++it) {
        const int idx = g + it * 131072;          // < 655360
        const int e = idx * 4;
        const int b = e / (TT * TT * LL);
        const int l = e % LL;
        float4 v = ((float4*)out)[idx];
        const float* ac = accum + b * LL + l;
        v.x -= __logf(ac[0]); v.y -= __logf(ac[1]);
        v.z -= __logf(ac[2]); v.w -= __logf(ac[3]);
        ((float4*)out)[idx] = v;
    }
}

extern "C" void kernel_launch(void* const* d_in, const int* in_sizes, int n_in,
                              void* d_out, int out_size, void* d_ws, size_t ws_size,
                              hipStream_t stream) {
    const float* hidden = (const float*)d_in[0];
    const float* W1     = (const float*)d_in[1];
    const float* b1     = (const float*)d_in[2];
    const float* W2     = (const float*)d_in[3];
    const float* b2     = (const float*)d_in[4];
    const int*   spans  = (const int*)d_in[5];
    const int*   avail  = (const int*)d_in[6];
    float* out = (float*)d_out;
    float* ws  = (float*)d_ws;

    void* args[] = {(void*)&hidden, (void*)&W1, (void*)&W2, (void*)&b1, (void*)&b2,
                    (void*)&spans, (void*)&avail, (void*)&out, (void*)&ws};
    hipLaunchCooperativeKernel((const void*)kFused, dim3(512), dim3(256), args, 0, stream);
}

// Round 6
// 137.257 us; speedup vs baseline: 2.3678x; 2.3678x over previous
//
#include <hip/hip_runtime.h>
#include <math.h>

#define BB 4
#define TT 128
#define DD 768
#define HD 770
#define HP 800
#define LL 40
#define TP1 129

typedef __attribute__((ext_vector_type(8))) short s16x8;
typedef __attribute__((ext_vector_type(4))) float f32x4;

// ws float offsets
#define P_OFF   0
#define Q_OFF   409600          // 512*800
#define W2F_OFF 819200          // 4800 uint4 = 19200 u32
#define ACC_OFF 838400          // 160 floats

__device__ __forceinline__ unsigned pkbf(float a, float b) {
    unsigned ua = __float_as_uint(a);
    unsigned ub = __float_as_uint(b);
    return ((ua + 0x8000u) >> 16) | ((ub + 0x8000u) & 0xffff0000u);
}
__device__ __forceinline__ unsigned rne1(float v) {
    unsigned x = __float_as_uint(v);
    return (x + 0x7fffu + ((x >> 16) & 1u)) >> 16;
}

// ============ kA: fused prep + X@W1 GEMM ============
// blocks [0,392): GEMM, wave=(mband 0..31, nt 0..48); B-frags packed in-register from W1
// blocks [392,411): W2 -> W2f fragments
// block  411:       zero accum
// blocks [412,472): zero Q pad cols [770,800)
__global__ __launch_bounds__(256) void kA(const float* __restrict__ hidden,
                                          const float* __restrict__ W1,
                                          const float* __restrict__ W2,
                                          const float* __restrict__ b1,
                                          float* __restrict__ P,
                                          float* __restrict__ Q,
                                          unsigned* __restrict__ W2f,
                                          float* __restrict__ accum) {
    const int bx  = blockIdx.x;
    const int tid = threadIdx.x;
    if (bx < 392) {
        const int wave = tid >> 6;
        const int lane = tid & 63;
        const int w = bx * 4 + wave;          // 0..1567
        const int mband = w & 31;
        const int nt = w >> 5;                // 0..48
        const int b  = mband >> 3;
        const int tt = mband & 7;
        const int col  = lane & 15;
        const int quad = lane >> 4;
        const int h = nt * 16 + col;          // may exceed 769 for nt=48 (unwritten)

        const float* __restrict__ Arow =
            hidden + (size_t)(b * TP1 + 1 + tt * 16 + col) * DD + quad * 8;

        f32x4 a0 = (f32x4){0.f, 0.f, 0.f, 0.f};
        f32x4 a1 = (f32x4){0.f, 0.f, 0.f, 0.f};

        #pragma unroll 2
        for (int ks = 0; ks < 24; ++ks) {
            // A fragment from hidden (fp32 -> bf16 in-register)
            float4 x0 = ((const float4*)(Arow + ks * 32))[0];
            float4 x1 = ((const float4*)(Arow + ks * 32))[1];
            union { unsigned u[4]; s16x8 v; } af;
            af.u[0] = pkbf(x0.x, x0.y); af.u[1] = pkbf(x0.z, x0.w);
            af.u[2] = pkbf(x1.x, x1.y); af.u[3] = pkbf(x1.z, x1.w);
            // B fragments from W1 directly (8 rows, stride HD; lanes 0..15 -> contiguous h)
            const int k0 = ks * 32 + quad * 8;
            const float* wp0 = W1 + (size_t)k0 * HD + h;            // W1a rows
            const float* wp1 = W1 + (size_t)(DD + k0) * HD + h;     // W1b rows
            union { unsigned u[4]; s16x8 v; } bf0, bf1;
            #pragma unroll
            for (int sp = 0; sp < 4; ++sp) {
                // in-bounds even for h>=770 (reads neighbor entries, outputs unwritten)
                bf0.u[sp] = rne1(wp0[(size_t)(2*sp) * HD]) |
                            (rne1(wp0[(size_t)(2*sp+1) * HD]) << 16);
                bf1.u[sp] = rne1(wp1[(size_t)(2*sp) * HD]) |
                            (rne1(wp1[(size_t)(2*sp+1) * HD]) << 16);
            }
            a0 = __builtin_amdgcn_mfma_f32_16x16x32_bf16(af.v, bf0.v, a0, 0, 0, 0);
            a1 = __builtin_amdgcn_mfma_f32_16x16x32_bf16(af.v, bf1.v, a1, 0, 0, 0);
        }

        if (h < HD) {
            const float bv = b1[h];
            #pragma unroll
            for (int r = 0; r < 4; ++r) {
                int t = tt * 16 + quad * 4 + r;
                size_t row = (size_t)(b * TT + t) * HP;
                P[row + h] = a0[r] + bv;
                Q[row + h] = a1[r];
            }
        }
    } else if (bx < 411) {
        int u = (bx - 392) * 256 + tid;
        if (u >= 4800) return;
        int nt = u / 1600;
        int rem = u - nt * 1600;
        int ks = rem >> 6;
        int ln = rem & 63;
        int kbase = ks * 32 + ((ln >> 4) << 3);
        int l = nt * 16 + (ln & 15);
        unsigned pk[4];
        #pragma unroll
        for (int sp = 0; sp < 4; ++sp) {
            unsigned wv[2];
            #pragma unroll
            for (int e = 0; e < 2; ++e) {
                int k = kbase + 2 * sp + e;
                float v = (k < HD && l < LL) ? W2[k * LL + l] : 0.0f;
                wv[e] = rne1(v);
            }
            pk[sp] = wv[0] | (wv[1] << 16);
        }
        ((uint4*)W2f)[u] = make_uint4(pk[0], pk[1], pk[2], pk[3]);
    } else if (bx == 411) {
        if (tid < 160) accum[tid] = 0.0f;
    } else {
        int u = (bx - 412) * 256 + tid;       // < 15360
        int row = u / 30;
        int h = HD + (u - row * 30);          // [770,800) only — no race with GEMM writes
        Q[(size_t)row * HP + h] = 0.0f;
    }
}

// ============ kB: MFMA (K-chunk 64, 13 barriers) + fused exp-sum ============
__global__ __launch_bounds__(256) void kB(const float* __restrict__ P,
                                          const float* __restrict__ Q,
                                          const float* __restrict__ W1,
                                          const unsigned* __restrict__ W2f,
                                          const float* __restrict__ b2,
                                          const int* __restrict__ spans,
                                          const int* __restrict__ avail,
                                          float* __restrict__ out,
                                          float* __restrict__ accum) {
    __shared__ unsigned Sb[2][128 * 33];   // 64 h per row (32 words) + 1 pad
    __shared__ float var[3 * HP];
    __shared__ int avi[TT];
    __shared__ float sred[192];

    const int i = blockIdx.x;
    const int b = blockIdx.y;
    const int tid = threadIdx.x;
    const int wave = tid >> 6;
    const int lane = tid & 63;

    const int start = spans[b * 2];
    const int end   = spans[b * 2 + 1];

    const int jS   = tid >> 1;
    const int half = tid & 1;              // which 32-h half of the 64-chunk
    int indS;
    {
        bool isfull = (i == start) && (jS == end);
        bool inside = (start <= i) && (i <= jS) && (jS <= end) && !isfull;
        indS = isfull ? 2 : (inside ? 1 : 0);
    }

    {
        const float* Pi  = P + (size_t)(b * TT + i) * HP;
        const float* w1L = W1 + (size_t)2 * DD * HD;
        for (int h = tid; h < HP; h += 256) {
            float pv = (h < HD) ? Pi[h] : 0.0f;
            float wv = (h < HD) ? w1L[h] : 0.0f;
            var[h]        = pv;
            var[HP + h]   = pv + wv;
            var[2*HP + h] = pv + wv + wv;
        }
        if (tid < TT) avi[tid] = avail[i * TT + tid];
    }
    __syncthreads();

    const float* Qj = Q + (size_t)(b * TT + jS) * HP;
    const float* vb = var + indS * HP;

    // pack 32 h (this thread's half of a 64-chunk) into Sb[p]
    auto form = [&](int c, int p, bool valid) {
        unsigned d[8];
        if (valid) {
            const int h0 = c * 64 + half * 32;
            const float4* qp = (const float4*)(Qj + h0);
            const float4* vp = (const float4*)(vb + h0);
            #pragma unroll
            for (int g = 0; g < 4; ++g) {
                float4 q0 = qp[2*g], q1 = qp[2*g + 1];
                float4 v0 = vp[2*g], v1 = vp[2*g + 1];
                float s0 = fmaxf(v0.x + q0.x, 0.f), s1 = fmaxf(v0.y + q0.y, 0.f);
                float s2 = fmaxf(v0.z + q0.z, 0.f), s3 = fmaxf(v0.w + q0.w, 0.f);
                float s4 = fmaxf(v1.x + q1.x, 0.f), s5 = fmaxf(v1.y + q1.y, 0.f);
                float s6 = fmaxf(v1.z + q1.z, 0.f), s7 = fmaxf(v1.w + q1.w, 0.f);
                d[2*g]   = pkbf(s0, s1) , d[2*g]   = pkbf(s0, s1);
                d[2*g]   = pkbf(s0, s1);
                d[2*g+1] = pkbf(s2, s3);
                // second float4 packs
                d[2*g]   = pkbf(s0, s1);
                d[2*g+1] = pkbf(s2, s3);
                // (s4..s7 packed below)
                (void)s4; (void)s5; (void)s6; (void)s7;
            }
            // redo cleanly: 32 floats -> 16 unsigneds
            const float4* qq = qp; const float4* vv = vp;
            unsigned e[16];
            #pragma unroll
            for (int g = 0; g < 8; ++g) {
                float4 qv = qq[g], vw = vv[g];
                float t0 = fmaxf(vw.x + qv.x, 0.f), t1 = fmaxf(vw.y + qv.y, 0.f);
                float t2 = fmaxf(vw.z + qv.z, 0.f), t3 = fmaxf(vw.w + qv.w, 0.f);
                e[2*g]   = pkbf(t0, t1);
                e[2*g+1] = pkbf(t2, t3);
            }
            uint4* dst = (uint4*)(&Sb[p][jS * 33 + half * 16]);
            dst[0] = make_uint4(e[0],  e[1],  e[2],  e[3]);
            dst[1] = make_uint4(e[4],  e[5],  e[6],  e[7]);
            dst[2] = make_uint4(e[8],  e[9],  e[10], e[11]);
            dst[3] = make_uint4(e[12], e[13], e[14], e[15]);
        } else {
            uint4* dst = (uint4*)(&Sb[p][jS * 33 + half * 16]);
            uint4 z = make_uint4(0u, 0u, 0u, 0u);
            dst[0] = z; dst[1] = z; dst[2] = z; dst[3] = z;
        }
    };

    f32x4 acc[2][3];
    #pragma unroll
    for (int mt = 0; mt < 2; ++mt)
        #pragma unroll
        for (int nt = 0; nt < 3; ++nt)
            acc[mt][nt] = (f32x4){0.f, 0.f, 0.f, 0.f};

    form(0, 0, true);
    __syncthreads();

    const int arow0 = (wave * 32 + (lane & 15)) * 33 + ((lane >> 4) << 2);
    const unsigned* W2fu = W2f;
    for (int c = 0; c < 13; ++c) {
        const int p = c & 1;
        const int ks0 = 2 * c;
        const int ks1 = (c < 12) ? (2 * c + 1) : 0;   // dummy 0 for tail (unused)
        s16x8 b00 = *(const s16x8*)(W2fu + (( 0 + ks0) * 64 + lane) * 4);
        s16x8 b01 = *(const s16x8*)(W2fu + ((25 + ks0) * 64 + lane) * 4);
        s16x8 b02 = *(const s16x8*)(W2fu + ((50 + ks0) * 64 + lane) * 4);
        s16x8 b10 = *(const s16x8*)(W2fu + (( 0 + ks1) * 64 + lane) * 4);
        s16x8 b11 = *(const s16x8*)(W2fu + ((25 + ks1) * 64 + lane) * 4);
        s16x8 b12 = *(const s16x8*)(W2fu + ((50 + ks1) * 64 + lane) * 4);
        s16x8 a00 = *(const s16x8*)(&Sb[p][arow0]);
        s16x8 a10 = *(const s16x8*)(&Sb[p][arow0 + 16 * 33]);
        s16x8 a01 = *(const s16x8*)(&Sb[p][arow0 + 16]);
        s16x8 a11 = *(const s16x8*)(&Sb[p][arow0 + 16 * 33 + 16]);
        if (c + 1 < 13) form(c + 1, p ^ 1, (c + 1 < 12) || (half == 0));
        acc[0][0] = __builtin_amdgcn_mfma_f32_16x16x32_bf16(a00, b00, acc[0][0], 0, 0, 0);
        acc[0][1] = __builtin_amdgcn_mfma_f32_16x16x32_bf16(a00, b01, acc[0][1], 0, 0, 0);
        acc[0][2] = __builtin_amdgcn_mfma_f32_16x16x32_bf16(a00, b02, acc[0][2], 0, 0, 0);
        acc[1][0] = __builtin_amdgcn_mfma_f32_16x16x32_bf16(a10, b00, acc[1][0], 0, 0, 0);
        acc[1][1] = __builtin_amdgcn_mfma_f32_16x16x32_bf16(a10, b01, acc[1][1], 0, 0, 0);
        acc[1][2] = __builtin_amdgcn_mfma_f32_16x16x32_bf16(a10, b02, acc[1][2], 0, 0, 0);
        if (c < 12) {
            acc[0][0] = __builtin_amdgcn_mfma_f32_16x16x32_bf16(a01, b10, acc[0][0], 0, 0, 0);
            acc[0][1] = __builtin_amdgcn_mfma_f32_16x16x32_bf16(a01, b11, acc[0][1], 0, 0, 0);
            acc[0][2] = __builtin_amdgcn_mfma_f32_16x16x32_bf16(a01, b12, acc[0][2], 0, 0, 0);
            acc[1][0] = __builtin_amdgcn_mfma_f32_16x16x32_bf16(a11, b10, acc[1][0], 0, 0, 0);
            acc[1][1] = __builtin_amdgcn_mfma_f32_16x16x32_bf16(a11, b11, acc[1][1], 0, 0, 0);
            acc[1][2] = __builtin_amdgcn_mfma_f32_16x16x32_bf16(a11, b12, acc[1][2], 0, 0, 0);
        }
        __syncthreads();
    }

    // epilogue: write out + accumulate exp-sums
    float bias[3];
    #pragma unroll
    for (int nt = 0; nt < 3; ++nt) {
        int l = nt * 16 + (lane & 15);
        bias[nt] = (l < LL) ? b2[l] : 0.0f;
    }
    const int jr0 = wave * 32 + ((lane >> 4) << 2);
    float sE[3] = {0.f, 0.f, 0.f};
    #pragma unroll
    for (int mt = 0; mt < 2; ++mt) {
        #pragma unroll
        for (int r = 0; r < 4; ++r) {
            int j = jr0 + mt * 16 + r;
            bool msk = avi[j] >= 1;
            size_t rowoff = ((size_t)(b * (TT * TT) + i * TT + j)) * LL;
            #pragma unroll
            for (int nt = 0; nt < 3; ++nt) {
                int l = nt * 16 + (lane & 15);
                if (l < LL) {
                    float val = msk ? (acc[mt][nt][r] + bias[nt]) : 0.0f;
                    out[rowoff + l] = val;
                    sE[nt] += __expf(val);
                }
            }
        }
    }
    #pragma unroll
    for (int nt = 0; nt < 3; ++nt) {
        float v = sE[nt];
        v += __shfl_xor(v, 16);
        v += __shfl_xor(v, 32);
        if (lane < 16) sred[wave * 48 + nt * 16 + lane] = v;
    }
    __syncthreads();
    if (tid < 48) {
        float t4 = sred[tid] + sred[48 + tid] + sred[96 + tid] + sred[144 + tid];
        if (tid < LL) atomicAdd(&accum[b * LL + tid], t4);
    }
}

// ============ kD: out -= log(denom) ============
__global__ __launch_bounds__(256) void kD(float* __restrict__ out,
                                          const float* __restrict__ accum) {
    const int idx = blockIdx.x * 256 + threadIdx.x;
    const int e = idx * 4;
    const int b = e / (TT * TT * LL);
    const int l = e % LL;
    float4 v = ((float4*)out)[idx];
    const float* ac = accum + b * LL + l;
    v.x -= __logf(ac[0]); v.y -= __logf(ac[1]);
    v.z -= __logf(ac[2]); v.w -= __logf(ac[3]);
    ((float4*)out)[idx] = v;
}

extern "C" void kernel_launch(void* const* d_in, const int* in_sizes, int n_in,
                              void* d_out, int out_size, void* d_ws, size_t ws_size,
                              hipStream_t stream) {
    const float* hidden = (const float*)d_in[0];
    const float* W1     = (const float*)d_in[1];
    const float* b1     = (const float*)d_in[2];
    const float* W2     = (const float*)d_in[3];
    const float* b2     = (const float*)d_in[4];
    const int*   spans  = (const int*)d_in[5];
    const int*   avail  = (const int*)d_in[6];
    float* out = (float*)d_out;
    float* ws  = (float*)d_ws;

    float*    P     = ws + P_OFF;
    float*    Q     = ws + Q_OFF;
    unsigned* W2f   = (unsigned*)(ws + W2F_OFF);
    float*    accum = ws + ACC_OFF;

    kA <<<dim3(472),    dim3(256), 0, stream>>>(hidden, W1, W2, b1, P, Q, W2f, accum);
    kB <<<dim3(TT, BB), dim3(256), 0, stream>>>(P, Q, W1, W2f, b2, spans, avail, out, accum);
    kD <<<dim3(2560),   dim3(256), 0, stream>>>(out, accum);
}